// Round 1
// baseline (1975.275 us; speedup 1.0000x reference)
//
#include <hip/hip_runtime.h>
#include <math.h>

// Problem geometry (B=8, N=4097, D=61, NPOINT=1024, NSAMPLE=16)
#define NB 8
#define NALL 4097
#define NPTS 4096            // N-1 points used for FPS/KNN
#define ND 61
#define NPOINT 1024
#define NS 16
#define XYZ_B_STRIDE 12291   // 4097*3
#define PTS_B_STRIDE 249917  // 4097*61
#define OUTXYZ_B 3075        // 1025*3
#define OUTPTS_B 131200      // 1025*128
#define OUT_PTS_OFF 24600    // 8*1025*3  (out_xyz block precedes out_pts)

// ---------------------------------------------------------------------------
// cls branch: 1 point per batch through 2-layer MLP. Also writes out_xyz[b,0].
// ---------------------------------------------------------------------------
__global__ __launch_bounds__(128)
void cls_kernel(const float* __restrict__ xyz, const float* __restrict__ pts,
                const float* __restrict__ w0, const float* __restrict__ b0,
                const float* __restrict__ g0, const float* __restrict__ bt0,
                const float* __restrict__ m0, const float* __restrict__ v0,
                const float* __restrict__ w1, const float* __restrict__ b1,
                const float* __restrict__ g1, const float* __restrict__ bt1,
                const float* __restrict__ m1, const float* __restrict__ v1,
                float* __restrict__ out)
{
    int b = blockIdx.x, t = threadIdx.x;
    __shared__ float in64[64];
    __shared__ float h[128];
    if (t < 64)
        in64[t] = (t < 3) ? xyz[b * XYZ_B_STRIDE + t]
                          : pts[(size_t)b * PTS_B_STRIDE + (t - 3)];
    __syncthreads();
    float A = g0[t] / sqrtf(v0[t] + 1e-5f);
    float B = (b0[t] - m0[t]) * A + bt0[t];
    float acc = 0.f;
    for (int c = 0; c < 64; ++c) acc = fmaf(w0[t * 64 + c], in64[c], acc);
    h[t] = fmaxf(acc * A + B, 0.f);
    __syncthreads();
    A = g1[t] / sqrtf(v1[t] + 1e-5f);
    B = (b1[t] - m1[t]) * A + bt1[t];
    acc = 0.f;
    for (int c = 0; c < 128; ++c) acc = fmaf(w1[t * 128 + c], h[c], acc);
    out[OUT_PTS_OFF + (size_t)b * OUTPTS_B + t] = fmaxf(acc * A + B, 0.f);
    if (t < 3) out[b * OUTXYZ_B + t] = xyz[b * XYZ_B_STRIDE + t];
}

// ---------------------------------------------------------------------------
// FPS: one block (256 thr) per batch. 1023 sequential argmax steps.
// All float math in round-to-nearest WITHOUT fma to match the numpy reference
// bit-exactly (discrete argmax decisions must match).
// Writes out_xyz rows 1..1024 and new_xyz(+|q|^2) to workspace.
// ---------------------------------------------------------------------------
__global__ __launch_bounds__(256)
void fps_kernel(const float* __restrict__ xyz, float4* __restrict__ nxyz,
                float* __restrict__ out)
{
    int b = blockIdx.x, tid = threadIdx.x;
    __shared__ float sx[NPTS], sy[NPTS], sz[NPTS];
    __shared__ float pv[4];
    __shared__ int   pi[4];
    __shared__ float4 res;

    float px[16], py[16], pz[16], dist[16];
    #pragma unroll
    for (int t = 0; t < 16; ++t) {
        int j = tid * 16 + t;
        const float* p = xyz + b * XYZ_B_STRIDE + 3 + j * 3;  // xyz_r = xyz[:,1:]
        float x = p[0], y = p[1], z = p[2];
        px[t] = x; py[t] = y; pz[t] = z; dist[t] = 1e10f;
        sx[j] = x; sy[j] = y; sz[j] = z;
    }
    __syncthreads();
    float cx = sx[0], cy = sy[0], cz = sz[0];  // far_0 = 0

    for (int s = 0;; ++s) {
        if (tid == 0) {
            float* o = out + b * OUTXYZ_B + 3 + s * 3;
            o[0] = cx; o[1] = cy; o[2] = cz;
            float s2 = __fadd_rn(__fadd_rn(__fmul_rn(cx, cx), __fmul_rn(cy, cy)),
                                 __fmul_rn(cz, cz));
            nxyz[b * NPOINT + s] = make_float4(cx, cy, cz, s2);
        }
        if (s == NPOINT - 1) break;

        float mv = -1.f; int mi = 0;
        #pragma unroll
        for (int t = 0; t < 16; ++t) {
            float dx = __fsub_rn(px[t], cx);
            float dy = __fsub_rn(py[t], cy);
            float dz = __fsub_rn(pz[t], cz);
            float d  = __fadd_rn(__fadd_rn(__fmul_rn(dx, dx), __fmul_rn(dy, dy)),
                                 __fmul_rn(dz, dz));
            float nd = fminf(dist[t], d);
            dist[t] = nd;
            if (nd > mv) { mv = nd; mi = tid * 16 + t; }  // tie -> smaller idx
        }
        // wave argmax, lexicographic (val desc, idx asc)
        #pragma unroll
        for (int off = 32; off; off >>= 1) {
            float ov = __shfl_xor(mv, off);
            int   oi = __shfl_xor(mi, off);
            if (ov > mv || (ov == mv && oi < mi)) { mv = ov; mi = oi; }
        }
        if ((tid & 63) == 0) { pv[tid >> 6] = mv; pi[tid >> 6] = mi; }
        __syncthreads();
        if (tid == 0) {
            float bv = pv[0]; int bi = pi[0];
            #pragma unroll
            for (int w = 1; w < 4; ++w)
                if (pv[w] > bv || (pv[w] == bv && pi[w] < bi)) { bv = pv[w]; bi = pi[w]; }
            res = make_float4(sx[bi], sy[bi], sz[bi], 0.f);
        }
        __syncthreads();
        float4 r = res; cx = r.x; cy = r.y; cz = r.z;
    }
}

// ---------------------------------------------------------------------------
// KNN: exact top-16 by (d2, idx). One wave per query row; 4 rows per block.
// d2 computed with the reference's expanded formula in rn arithmetic.
// ---------------------------------------------------------------------------
__global__ __launch_bounds__(256)
void knn_kernel(const float* __restrict__ xyz, const float4* __restrict__ nxyz,
                int* __restrict__ knn)
{
    int bb = blockIdx.x, tid = threadIdx.x;
    int b = bb >> 8;                 // 256 blocks per batch
    int sbase = (bb & 255) * 4;
    __shared__ float sx[NPTS], sy[NPTS], sz[NPTS], sn[NPTS];
    #pragma unroll 1
    for (int t = 0; t < 16; ++t) {
        int j = tid + t * 256;
        const float* p = xyz + b * XYZ_B_STRIDE + 3 + j * 3;
        float x = p[0], y = p[1], z = p[2];
        sx[j] = x; sy[j] = y; sz[j] = z;
        sn[j] = __fadd_rn(__fadd_rn(__fmul_rn(x, x), __fmul_rn(y, y)), __fmul_rn(z, z));
    }
    __syncthreads();
    int wid = tid >> 6, lane = tid & 63;
    int r = b * NPOINT + sbase + wid;
    float4 q = nxyz[r];

    float sv[16]; int si[16];
    #pragma unroll
    for (int k = 0; k < 16; ++k) { sv[k] = 3.0e38f; si[k] = 0x7fffffff; }

    #pragma unroll 1
    for (int t = 0; t < 64; ++t) {
        int j = (t << 6) + lane;
        float dot = __fadd_rn(__fadd_rn(__fmul_rn(q.x, sx[j]), __fmul_rn(q.y, sy[j])),
                              __fmul_rn(q.z, sz[j]));
        float d2 = __fsub_rn(__fadd_rn(q.w, sn[j]), __fmul_rn(2.0f, dot));
        if (d2 < sv[15]) {            // strict <: equal value keeps earlier index
            sv[15] = d2; si[15] = j;
            #pragma unroll
            for (int k = 15; k > 0; --k) {
                if (sv[k] < sv[k - 1]) {
                    float tv = sv[k]; sv[k] = sv[k - 1]; sv[k - 1] = tv;
                    int   ti = si[k]; si[k] = si[k - 1]; si[k - 1] = ti;
                }
            }
        }
    }
    // merge 64 sorted lists: 16 rounds of wave argmin over the heads
    int mykn = 0;
    #pragma unroll 1
    for (int it = 0; it < 16; ++it) {
        float bvv = sv[0]; int bii = si[0];
        #pragma unroll
        for (int off = 32; off; off >>= 1) {
            float ov = __shfl_xor(bvv, off);
            int   oi = __shfl_xor(bii, off);
            if (ov < bvv || (ov == bvv && oi < bii)) { bvv = ov; bii = oi; }
        }
        if (lane == it) mykn = bii;
        bool win = (sv[0] == bvv) && (si[0] == bii);   // idx unique -> one winner
        if (win) {
            #pragma unroll
            for (int k = 0; k < 15; ++k) { sv[k] = sv[k + 1]; si[k] = si[k + 1]; }
            sv[15] = 3.0e38f; si[15] = 0x7fffffff;
        }
    }
    if (lane < 16) knn[r * NS + lane] = mykn;
}

// ---------------------------------------------------------------------------
// Gather + MLP(64->128->128) + maxpool over 16 neighbors. 128 thr = one output
// channel each; W rows held in VGPRs; 8 rows per block amortize the W load.
// ---------------------------------------------------------------------------
__global__ __launch_bounds__(128)
void mlp_kernel(const float* __restrict__ xyz, const float* __restrict__ pts,
                const float4* __restrict__ nxyz, const int* __restrict__ knn,
                const float* __restrict__ w0, const float* __restrict__ b0,
                const float* __restrict__ g0, const float* __restrict__ bt0,
                const float* __restrict__ m0, const float* __restrict__ v0,
                const float* __restrict__ w1, const float* __restrict__ b1,
                const float* __restrict__ g1, const float* __restrict__ bt1,
                const float* __restrict__ m1, const float* __restrict__ v1,
                float* __restrict__ out)
{
    int bb = blockIdx.x, tid = threadIdx.x;
    __shared__ float feat[16 * 64];
    __shared__ float hbuf[16 * 128];
    __shared__ int   kk[16];

    float4 w0r[16], w1r[32];
    const float4* w0p = (const float4*)(w0 + tid * 64);
    #pragma unroll
    for (int i = 0; i < 16; ++i) w0r[i] = w0p[i];
    const float4* w1p = (const float4*)(w1 + tid * 128);
    #pragma unroll
    for (int i = 0; i < 32; ++i) w1r[i] = w1p[i];
    float A0 = g0[tid] / sqrtf(v0[tid] + 1e-5f);
    float B0 = (b0[tid] - m0[tid]) * A0 + bt0[tid];
    float A1 = g1[tid] / sqrtf(v1[tid] + 1e-5f);
    float B1 = (b1[tid] - m1[tid]) * A1 + bt1[tid];

    int r0 = bb * 8;
    int b = r0 >> 10;                 // 8 rows share one batch (8 | 1024)
    for (int qq = 0; qq < 8; ++qq) {
        int r = r0 + qq;
        int s = r & 1023;
        if (tid < 16) kk[tid] = knn[r * NS + tid];
        __syncthreads();
        float4 nq = nxyz[r];
        #pragma unroll
        for (int i = 0; i < 8; ++i) {
            int e = tid + (i << 7);
            int k = e >> 6, c = e & 63;
            int j = kk[k];
            float v;
            if (c < 3) {
                float g = xyz[b * XYZ_B_STRIDE + 3 + j * 3 + c];
                float n = (c == 0) ? nq.x : ((c == 1) ? nq.y : nq.z);
                v = __fsub_rn(g, n);   // g_xyz bit-exact
            } else {
                v = pts[(size_t)b * PTS_B_STRIDE + 61 + (size_t)j * 61 + (c - 3)];
            }
            feat[e] = v;
        }
        __syncthreads();
        #pragma unroll 1
        for (int k = 0; k < 16; ++k) {
            const float4* fv = (const float4*)(feat + (k << 6));
            float acc = 0.f;
            #pragma unroll
            for (int i = 0; i < 16; ++i) {
                float4 f = fv[i];
                acc = fmaf(w0r[i].x, f.x, acc);
                acc = fmaf(w0r[i].y, f.y, acc);
                acc = fmaf(w0r[i].z, f.z, acc);
                acc = fmaf(w0r[i].w, f.w, acc);
            }
            hbuf[(k << 7) + tid] = fmaxf(acc * A0 + B0, 0.f);
        }
        __syncthreads();
        float mx = 0.f;                 // relu outputs >= 0 so 0 is a safe init
        #pragma unroll 1
        for (int k = 0; k < 16; ++k) {
            const float4* hv = (const float4*)(hbuf + (k << 7));
            float acc = 0.f;
            #pragma unroll
            for (int i = 0; i < 32; ++i) {
                float4 f = hv[i];
                acc = fmaf(w1r[i].x, f.x, acc);
                acc = fmaf(w1r[i].y, f.y, acc);
                acc = fmaf(w1r[i].z, f.z, acc);
                acc = fmaf(w1r[i].w, f.w, acc);
            }
            mx = fmaxf(mx, fmaxf(acc * A1 + B1, 0.f));
        }
        out[OUT_PTS_OFF + (size_t)b * OUTPTS_B + (size_t)(1 + s) * 128 + tid] = mx;
        __syncthreads();   // protect kk/feat for next row
    }
}

// ---------------------------------------------------------------------------
extern "C" void kernel_launch(void* const* d_in, const int* in_sizes, int n_in,
                              void* d_out, int out_size, void* d_ws, size_t ws_size,
                              hipStream_t stream) {
    const float* xyz = (const float*)d_in[0];
    const float* pts = (const float*)d_in[1];
    // dict order: sa0 block, cls0 block, sa1 block, cls1 block
    const float* sa_w0 = (const float*)d_in[2];
    const float* sa_b0 = (const float*)d_in[3];
    const float* sa_g0 = (const float*)d_in[4];
    const float* sa_bt0 = (const float*)d_in[5];
    const float* sa_m0 = (const float*)d_in[6];
    const float* sa_v0 = (const float*)d_in[7];
    const float* cls_w0 = (const float*)d_in[8];
    const float* cls_b0 = (const float*)d_in[9];
    const float* cls_g0 = (const float*)d_in[10];
    const float* cls_bt0 = (const float*)d_in[11];
    const float* cls_m0 = (const float*)d_in[12];
    const float* cls_v0 = (const float*)d_in[13];
    const float* sa_w1 = (const float*)d_in[14];
    const float* sa_b1 = (const float*)d_in[15];
    const float* sa_g1 = (const float*)d_in[16];
    const float* sa_bt1 = (const float*)d_in[17];
    const float* sa_m1 = (const float*)d_in[18];
    const float* sa_v1 = (const float*)d_in[19];
    const float* cls_w1 = (const float*)d_in[20];
    const float* cls_b1 = (const float*)d_in[21];
    const float* cls_g1 = (const float*)d_in[22];
    const float* cls_bt1 = (const float*)d_in[23];
    const float* cls_m1 = (const float*)d_in[24];
    const float* cls_v1 = (const float*)d_in[25];

    float* out = (float*)d_out;
    float4* nxyz_ws = (float4*)d_ws;                          // 8192 * 16 B
    int* knn_ws = (int*)((char*)d_ws + NB * NPOINT * sizeof(float4));

    cls_kernel<<<NB, 128, 0, stream>>>(xyz, pts,
        cls_w0, cls_b0, cls_g0, cls_bt0, cls_m0, cls_v0,
        cls_w1, cls_b1, cls_g1, cls_bt1, cls_m1, cls_v1, out);
    fps_kernel<<<NB, 256, 0, stream>>>(xyz, nxyz_ws, out);
    knn_kernel<<<NB * (NPOINT / 4), 256, 0, stream>>>(xyz, nxyz_ws, knn_ws);
    mlp_kernel<<<NB * NPOINT / 8, 128, 0, stream>>>(xyz, pts, nxyz_ws, knn_ws,
        sa_w0, sa_b0, sa_g0, sa_bt0, sa_m0, sa_v0,
        sa_w1, sa_b1, sa_g1, sa_bt1, sa_m1, sa_v1, out);
}

// Round 2
// 1346.442 us; speedup vs baseline: 1.4670x; 1.4670x over previous
//
#include <hip/hip_runtime.h>
#include <math.h>

// Problem geometry (B=8, N=4097, D=61, NPOINT=1024, NSAMPLE=16)
#define NB 8
#define NALL 4097
#define NPTS 4096            // N-1 points used for FPS/KNN
#define ND 61
#define NPOINT 1024
#define NS 16
#define XYZ_B_STRIDE 12291   // 4097*3
#define PTS_B_STRIDE 249917  // 4097*61
#define OUTXYZ_B 3075        // 1025*3
#define OUTPTS_B 131200      // 1025*128
#define OUT_PTS_OFF 24600    // 8*1025*3  (out_xyz block precedes out_pts)

// ---------------------------------------------------------------------------
// cls branch: 1 point per batch through 2-layer MLP. Also writes out_xyz[b,0].
// ---------------------------------------------------------------------------
__global__ __launch_bounds__(128)
void cls_kernel(const float* __restrict__ xyz, const float* __restrict__ pts,
                const float* __restrict__ w0, const float* __restrict__ b0,
                const float* __restrict__ g0, const float* __restrict__ bt0,
                const float* __restrict__ m0, const float* __restrict__ v0,
                const float* __restrict__ w1, const float* __restrict__ b1,
                const float* __restrict__ g1, const float* __restrict__ bt1,
                const float* __restrict__ m1, const float* __restrict__ v1,
                float* __restrict__ out)
{
    int b = blockIdx.x, t = threadIdx.x;
    __shared__ float in64[64];
    __shared__ float h[128];
    if (t < 64)
        in64[t] = (t < 3) ? xyz[b * XYZ_B_STRIDE + t]
                          : pts[(size_t)b * PTS_B_STRIDE + (t - 3)];
    __syncthreads();
    float A = g0[t] / sqrtf(v0[t] + 1e-5f);
    float B = (b0[t] - m0[t]) * A + bt0[t];
    float acc = 0.f;
    for (int c = 0; c < 64; ++c) acc = fmaf(w0[t * 64 + c], in64[c], acc);
    h[t] = fmaxf(acc * A + B, 0.f);
    __syncthreads();
    A = g1[t] / sqrtf(v1[t] + 1e-5f);
    B = (b1[t] - m1[t]) * A + bt1[t];
    acc = 0.f;
    for (int c = 0; c < 128; ++c) acc = fmaf(w1[t * 128 + c], h[c], acc);
    out[OUT_PTS_OFF + (size_t)b * OUTPTS_B + t] = fmaxf(acc * A + B, 0.f);
    if (t < 3) out[b * OUTXYZ_B + t] = xyz[b * XYZ_B_STRIDE + t];
}

// ---------------------------------------------------------------------------
// FPS: one block (256 thr = 4 waves) per batch. 1023 serial argmax steps.
// R1 changes vs R0 (critical-path surgery):
//   - NO global stores in the loop (centers buffered in LDS, written at end)
//     -> no s_waitcnt vmcnt(0) drain before each barrier.
//   - ONE barrier per step: per-wave results go to parity-double-buffered
//     LDS slots; all threads redundantly combine 4 wave results.
//   - wave argmax via DPP max chain (pure VALU) + ballot + readlane instead
//     of 6 dependent ds_swizzle shuffle rounds.
// All float math round-to-nearest, NO fma contraction (numpy bit-exactness
// of the discrete argmax decisions).
// ---------------------------------------------------------------------------
#define DPP_MAXSTEP(x, ctrl)                                                   \
    x = fmaxf(x, __int_as_float(__builtin_amdgcn_update_dpp(                   \
            0, __float_as_int(x), ctrl, 0xf, 0xf, true)))

__global__ __launch_bounds__(256)
void fps_kernel(const float* __restrict__ xyz, float4* __restrict__ nxyz,
                float* __restrict__ out)
{
#pragma clang fp contract(off)
    int b = blockIdx.x, tid = threadIdx.x;
    __shared__ float sx[NPTS], sy[NPTS], sz[NPTS];
    __shared__ float cbx[NPOINT], cby[NPOINT], cbz[NPOINT];
    __shared__ float2 pvpi[2][4];

    float px[16], py[16], pz[16], dist[16];
    #pragma unroll
    for (int t = 0; t < 16; ++t) {
        int j = tid * 16 + t;
        const float* p = xyz + b * XYZ_B_STRIDE + 3 + j * 3;  // xyz_r = xyz[:,1:]
        float x = p[0], y = p[1], z = p[2];
        px[t] = x; py[t] = y; pz[t] = z; dist[t] = 1e10f;
        sx[j] = x; sy[j] = y; sz[j] = z;
    }
    __syncthreads();
    float cx = sx[0], cy = sy[0], cz = sz[0];  // far_0 = 0
    if (tid == 0) { cbx[0] = cx; cby[0] = cy; cbz[0] = cz; }

    for (int s = 0; s < NPOINT - 1; ++s) {
        float mv = -1.f; int mi = 0;
        #pragma unroll
        for (int t = 0; t < 16; ++t) {
            float dx = px[t] - cx;
            float dy = py[t] - cy;
            float dz = pz[t] - cz;
            float d  = (dx * dx + dy * dy) + dz * dz;   // contract(off): rn mul/add
            float nd = fminf(dist[t], d);
            dist[t] = nd;
            if (nd > mv) { mv = nd; mi = tid * 16 + t; }  // tie -> smaller idx
        }
        // wave max via DPP (dist >= 0, bound_ctrl zero-fill is harmless)
        float w = mv;
        DPP_MAXSTEP(w, 0x111);   // row_shr:1
        DPP_MAXSTEP(w, 0x112);   // row_shr:2
        DPP_MAXSTEP(w, 0x114);   // row_shr:4
        DPP_MAXSTEP(w, 0x118);   // row_shr:8
        DPP_MAXSTEP(w, 0x142);   // row_bcast:15
        DPP_MAXSTEP(w, 0x143);   // row_bcast:31  -> lane 63 has wave max
        float wmax = __shfl(w, 63);
        // lanes are index-ordered and per-lane mi is first-max -> lowest
        // ballot lane holds the smallest qualifying global index
        unsigned long long ball = __ballot(mv == wmax);
        int first = __ffsll((long long)ball) - 1;
        int bwi = __builtin_amdgcn_readlane(mi, first);
        int par = s & 1;
        if ((tid & 63) == 0)
            pvpi[par][tid >> 6] = make_float2(wmax, __int_as_float(bwi));
        __syncthreads();
        float2 q0 = pvpi[par][0], q1 = pvpi[par][1];
        float2 q2 = pvpi[par][2], q3 = pvpi[par][3];
        float bv = q0.x; int bi = __float_as_int(q0.y);
        if (q1.x > bv) { bv = q1.x; bi = __float_as_int(q1.y); }
        if (q2.x > bv) { bv = q2.x; bi = __float_as_int(q2.y); }
        if (q3.x > bv) { bv = q3.x; bi = __float_as_int(q3.y); }
        cx = sx[bi]; cy = sy[bi]; cz = sz[bi];
        if (tid == 0) { cbx[s + 1] = cx; cby[s + 1] = cy; cbz[s + 1] = cz; }
    }
    __syncthreads();
    // single writeout of all centers (+|q|^2 for KNN)
    for (int s = tid; s < NPOINT; s += 256) {
        float x = cbx[s], y = cby[s], z = cbz[s];
        float s2 = (x * x + y * y) + z * z;   // rn, same assoc as reference
        float* o = out + b * OUTXYZ_B + 3 + s * 3;
        o[0] = x; o[1] = y; o[2] = z;
        nxyz[b * NPOINT + s] = make_float4(x, y, z, s2);
    }
}

// ---------------------------------------------------------------------------
// KNN: exact top-16 by (d2, idx). One wave per query row; 4 rows per block.
// d2 computed with the reference's expanded formula in rn arithmetic.
// ---------------------------------------------------------------------------
__global__ __launch_bounds__(256)
void knn_kernel(const float* __restrict__ xyz, const float4* __restrict__ nxyz,
                int* __restrict__ knn)
{
    int bb = blockIdx.x, tid = threadIdx.x;
    int b = bb >> 8;                 // 256 blocks per batch
    int sbase = (bb & 255) * 4;
    __shared__ float sx[NPTS], sy[NPTS], sz[NPTS], sn[NPTS];
    #pragma unroll 1
    for (int t = 0; t < 16; ++t) {
        int j = tid + t * 256;
        const float* p = xyz + b * XYZ_B_STRIDE + 3 + j * 3;
        float x = p[0], y = p[1], z = p[2];
        sx[j] = x; sy[j] = y; sz[j] = z;
        sn[j] = __fadd_rn(__fadd_rn(__fmul_rn(x, x), __fmul_rn(y, y)), __fmul_rn(z, z));
    }
    __syncthreads();
    int wid = tid >> 6, lane = tid & 63;
    int r = b * NPOINT + sbase + wid;
    float4 q = nxyz[r];

    float sv[16]; int si[16];
    #pragma unroll
    for (int k = 0; k < 16; ++k) { sv[k] = 3.0e38f; si[k] = 0x7fffffff; }

    #pragma unroll 1
    for (int t = 0; t < 64; ++t) {
        int j = (t << 6) + lane;
        float dot = __fadd_rn(__fadd_rn(__fmul_rn(q.x, sx[j]), __fmul_rn(q.y, sy[j])),
                              __fmul_rn(q.z, sz[j]));
        float d2 = __fsub_rn(__fadd_rn(q.w, sn[j]), __fmul_rn(2.0f, dot));
        if (d2 < sv[15]) {            // strict <: equal value keeps earlier index
            sv[15] = d2; si[15] = j;
            #pragma unroll
            for (int k = 15; k > 0; --k) {
                if (sv[k] < sv[k - 1]) {
                    float tv = sv[k]; sv[k] = sv[k - 1]; sv[k - 1] = tv;
                    int   ti = si[k]; si[k] = si[k - 1]; si[k - 1] = ti;
                }
            }
        }
    }
    // merge 64 sorted lists: 16 rounds of wave argmin over the heads
    int mykn = 0;
    #pragma unroll 1
    for (int it = 0; it < 16; ++it) {
        float bvv = sv[0]; int bii = si[0];
        #pragma unroll
        for (int off = 32; off; off >>= 1) {
            float ov = __shfl_xor(bvv, off);
            int   oi = __shfl_xor(bii, off);
            if (ov < bvv || (ov == bvv && oi < bii)) { bvv = ov; bii = oi; }
        }
        if (lane == it) mykn = bii;
        bool win = (sv[0] == bvv) && (si[0] == bii);   // idx unique -> one winner
        if (win) {
            #pragma unroll
            for (int k = 0; k < 15; ++k) { sv[k] = sv[k + 1]; si[k] = si[k + 1]; }
            sv[15] = 3.0e38f; si[15] = 0x7fffffff;
        }
    }
    if (lane < 16) knn[r * NS + lane] = mykn;
}

// ---------------------------------------------------------------------------
// Gather + MLP(64->128->128) + maxpool over 16 neighbors. 128 thr = one output
// channel each; W rows held in VGPRs; 8 rows per block amortize the W load.
// ---------------------------------------------------------------------------
__global__ __launch_bounds__(128)
void mlp_kernel(const float* __restrict__ xyz, const float* __restrict__ pts,
                const float4* __restrict__ nxyz, const int* __restrict__ knn,
                const float* __restrict__ w0, const float* __restrict__ b0,
                const float* __restrict__ g0, const float* __restrict__ bt0,
                const float* __restrict__ m0, const float* __restrict__ v0,
                const float* __restrict__ w1, const float* __restrict__ b1,
                const float* __restrict__ g1, const float* __restrict__ bt1,
                const float* __restrict__ m1, const float* __restrict__ v1,
                float* __restrict__ out)
{
    int bb = blockIdx.x, tid = threadIdx.x;
    __shared__ float feat[16 * 64];
    __shared__ float hbuf[16 * 128];
    __shared__ int   kk[16];

    float4 w0r[16], w1r[32];
    const float4* w0p = (const float4*)(w0 + tid * 64);
    #pragma unroll
    for (int i = 0; i < 16; ++i) w0r[i] = w0p[i];
    const float4* w1p = (const float4*)(w1 + tid * 128);
    #pragma unroll
    for (int i = 0; i < 32; ++i) w1r[i] = w1p[i];
    float A0 = g0[tid] / sqrtf(v0[tid] + 1e-5f);
    float B0 = (b0[tid] - m0[tid]) * A0 + bt0[tid];
    float A1 = g1[tid] / sqrtf(v1[tid] + 1e-5f);
    float B1 = (b1[tid] - m1[tid]) * A1 + bt1[tid];

    int r0 = bb * 8;
    int b = r0 >> 10;                 // 8 rows share one batch (8 | 1024)
    for (int qq = 0; qq < 8; ++qq) {
        int r = r0 + qq;
        int s = r & 1023;
        if (tid < 16) kk[tid] = knn[r * NS + tid];
        __syncthreads();
        float4 nq = nxyz[r];
        #pragma unroll
        for (int i = 0; i < 8; ++i) {
            int e = tid + (i << 7);
            int k = e >> 6, c = e & 63;
            int j = kk[k];
            float v;
            if (c < 3) {
                float g = xyz[b * XYZ_B_STRIDE + 3 + j * 3 + c];
                float n = (c == 0) ? nq.x : ((c == 1) ? nq.y : nq.z);
                v = __fsub_rn(g, n);   // g_xyz bit-exact
            } else {
                v = pts[(size_t)b * PTS_B_STRIDE + 61 + (size_t)j * 61 + (c - 3)];
            }
            feat[e] = v;
        }
        __syncthreads();
        #pragma unroll 1
        for (int k = 0; k < 16; ++k) {
            const float4* fv = (const float4*)(feat + (k << 6));
            float acc = 0.f;
            #pragma unroll
            for (int i = 0; i < 16; ++i) {
                float4 f = fv[i];
                acc = fmaf(w0r[i].x, f.x, acc);
                acc = fmaf(w0r[i].y, f.y, acc);
                acc = fmaf(w0r[i].z, f.z, acc);
                acc = fmaf(w0r[i].w, f.w, acc);
            }
            hbuf[(k << 7) + tid] = fmaxf(acc * A0 + B0, 0.f);
        }
        __syncthreads();
        float mx = 0.f;                 // relu outputs >= 0 so 0 is a safe init
        #pragma unroll 1
        for (int k = 0; k < 16; ++k) {
            const float4* hv = (const float4*)(hbuf + (k << 7));
            float acc = 0.f;
            #pragma unroll
            for (int i = 0; i < 32; ++i) {
                float4 f = hv[i];
                acc = fmaf(w1r[i].x, f.x, acc);
                acc = fmaf(w1r[i].y, f.y, acc);
                acc = fmaf(w1r[i].z, f.z, acc);
                acc = fmaf(w1r[i].w, f.w, acc);
            }
            mx = fmaxf(mx, fmaxf(acc * A1 + B1, 0.f));
        }
        out[OUT_PTS_OFF + (size_t)b * OUTPTS_B + (size_t)(1 + s) * 128 + tid] = mx;
        __syncthreads();   // protect kk/feat for next row
    }
}

// ---------------------------------------------------------------------------
extern "C" void kernel_launch(void* const* d_in, const int* in_sizes, int n_in,
                              void* d_out, int out_size, void* d_ws, size_t ws_size,
                              hipStream_t stream) {
    const float* xyz = (const float*)d_in[0];
    const float* pts = (const float*)d_in[1];
    // dict order: sa0 block, cls0 block, sa1 block, cls1 block
    const float* sa_w0 = (const float*)d_in[2];
    const float* sa_b0 = (const float*)d_in[3];
    const float* sa_g0 = (const float*)d_in[4];
    const float* sa_bt0 = (const float*)d_in[5];
    const float* sa_m0 = (const float*)d_in[6];
    const float* sa_v0 = (const float*)d_in[7];
    const float* cls_w0 = (const float*)d_in[8];
    const float* cls_b0 = (const float*)d_in[9];
    const float* cls_g0 = (const float*)d_in[10];
    const float* cls_bt0 = (const float*)d_in[11];
    const float* cls_m0 = (const float*)d_in[12];
    const float* cls_v0 = (const float*)d_in[13];
    const float* sa_w1 = (const float*)d_in[14];
    const float* sa_b1 = (const float*)d_in[15];
    const float* sa_g1 = (const float*)d_in[16];
    const float* sa_bt1 = (const float*)d_in[17];
    const float* sa_m1 = (const float*)d_in[18];
    const float* sa_v1 = (const float*)d_in[19];
    const float* cls_w1 = (const float*)d_in[20];
    const float* cls_b1 = (const float*)d_in[21];
    const float* cls_g1 = (const float*)d_in[22];
    const float* cls_bt1 = (const float*)d_in[23];
    const float* cls_m1 = (const float*)d_in[24];
    const float* cls_v1 = (const float*)d_in[25];

    float* out = (float*)d_out;
    float4* nxyz_ws = (float4*)d_ws;                          // 8192 * 16 B
    int* knn_ws = (int*)((char*)d_ws + NB * NPOINT * sizeof(float4));

    cls_kernel<<<NB, 128, 0, stream>>>(xyz, pts,
        cls_w0, cls_b0, cls_g0, cls_bt0, cls_m0, cls_v0,
        cls_w1, cls_b1, cls_g1, cls_bt1, cls_m1, cls_v1, out);
    fps_kernel<<<NB, 256, 0, stream>>>(xyz, nxyz_ws, out);
    knn_kernel<<<NB * (NPOINT / 4), 256, 0, stream>>>(xyz, nxyz_ws, knn_ws);
    mlp_kernel<<<NB * NPOINT / 8, 128, 0, stream>>>(xyz, pts, nxyz_ws, knn_ws,
        sa_w0, sa_b0, sa_g0, sa_bt0, sa_m0, sa_v0,
        sa_w1, sa_b1, sa_g1, sa_bt1, sa_m1, sa_v1, out);
}